// Round 5
// baseline (116.091 us; speedup 1.0000x reference)
//
#include <hip/hip_runtime.h>
#include <hip/hip_bf16.h>
#include <math.h>

#define Bsz 8
#define Nsz 1024
#define FIN 128
#define Hh  4
#define FO  64
#define COLS 256   // Hh*FO
#define TN  16
#define TM  32
#define BN  (Bsz*Nsz)
#define SHIFT 12.0f
#define HSTR 40    // ushort stride per c-row of attn h-tile (32 data + 8 pad)
#define PSTR 136   // ushort stride per r-row of p-tile (128 data + 8 pad)

typedef __attribute__((ext_vector_type(8))) short short8;
typedef __attribute__((ext_vector_type(4))) float f32x4;
typedef __attribute__((ext_vector_type(2))) float f32x2;

static __device__ inline ushort f2bf(float f) {           // RNE float->bf16
    uint u = __float_as_uint(f);
    u += 0x7FFFu + ((u >> 16) & 1u);
    return (ushort)(u >> 16);
}
static __device__ inline uint cvt_pk2(float lo, float hi) {  // packed RNE pair -> bf16x2 bits
    union { __hip_bfloat162 h; uint u; } cv;
    cv.h = __float22bfloat162_rn(float2{lo, hi});
    return cv.u;
}

// ---------------- prep: Wt[n][k] = bf16(W[k][n]) ----------------
__global__ __launch_bounds__(256) void gat_prep(const float* __restrict__ W,
                                                ushort* __restrict__ Wt)
{
    const int g = blockIdx.x * 256 + threadIdx.x;   // 0..2047
    const int n = g >> 3, kc = (g & 7) * 16;
    ushort u[16];
    #pragma unroll
    for (int i = 0; i < 16; i++) u[i] = f2bf(W[(kc + i) * COLS + n]);
    int4* dst = (int4*)(Wt + n * FIN + kc);
    dst[0] = ((int4*)u)[0];
    dst[1] = ((int4*)u)[1];
}

// ---------------- Kernel A: h = x@W via MFMA, no LDS, no barrier ----------------
// grid 512 = (b, 16-row tile), 256 thr. Wave w = head w. A-frags direct from x
// (8 k-consecutive floats/lane = 2 float4), B-frags from L2-hot Wt.
__global__ __launch_bounds__(256) void gat_proj(
    const float* __restrict__ x, const ushort* __restrict__ Wt,
    const float* __restrict__ a, ushort* __restrict__ h_gB,
    float* __restrict__ es_g, float* __restrict__ ed_g)
{
    const int j    = threadIdx.x;
    const int w    = j >> 6, lane = j & 63, quad = lane >> 4, n16 = lane & 15;
    const int b    = blockIdx.x >> 6, mt16 = blockIdx.x & 63;
    const long rowbase = (long)b * Nsz + mt16 * 16;

    // B fragments (16 x b128 from Wt)
    short8 bfr[4][4];
    #pragma unroll
    for (int kk = 0; kk < 4; kk++)
        #pragma unroll
        for (int c4 = 0; c4 < 4; c4++)
            bfr[kk][c4] = *(const short8*)(Wt + (w*64 + c4*16 + n16) * FIN + kk*32 + quad*8);

    // A fragments direct from x: row = rowbase + n16, k = kk*32 + quad*8 + 0..7
    short8 af[4];
    const float* xr = x + (rowbase + n16) * FIN + quad * 8;
    #pragma unroll
    for (int kk = 0; kk < 4; kk++) {
        float4 v0 = *(const float4*)(xr + kk*32);
        float4 v1 = *(const float4*)(xr + kk*32 + 4);
        union { uint u[4]; short8 s; } pk;
        pk.u[0] = cvt_pk2(v0.x, v0.y); pk.u[1] = cvt_pk2(v0.z, v0.w);
        pk.u[2] = cvt_pk2(v1.x, v1.y); pk.u[3] = cvt_pk2(v1.z, v1.w);
        af[kk] = pk.s;
    }

    f32x4 acc[4];
    #pragma unroll
    for (int c4 = 0; c4 < 4; c4++)
        #pragma unroll
        for (int r = 0; r < 4; r++) acc[c4][r] = 0.f;

    #pragma unroll
    for (int kk = 0; kk < 4; kk++)
        #pragma unroll
        for (int c4 = 0; c4 < 4; c4++)
            acc[c4] = __builtin_amdgcn_mfma_f32_16x16x32_bf16(af[kk], bfr[kk][c4], acc[c4], 0, 0, 0);

    // ---- h_gB store: [b][mt=row/32][c][k=row%32] bf16 (C row = quad*4+reg) ----
    const int mtile = mt16 >> 1;
    const int kbase = (mt16 & 1) * 16 + quad * 4;
    #pragma unroll
    for (int c4 = 0; c4 < 4; c4++) {
        uint2 pk;
        pk.x = cvt_pk2(acc[c4][0], acc[c4][1]);
        pk.y = cvt_pk2(acc[c4][2], acc[c4][3]);
        const int c = w*64 + c4*16 + n16;
        *(uint2*)(h_gB + (((long)(b*32 + mtile) * COLS + c) * 32 + kbase)) = pk;
    }

    // ---- es/ed from fp32 accumulators ----
    float aS[4], aD[4];
    #pragma unroll
    for (int c4 = 0; c4 < 4; c4++) {
        aS[c4] = a[w * (2*FO) + c4*16 + n16];
        aD[c4] = a[w * (2*FO) + FO + c4*16 + n16];
    }
    #pragma unroll
    for (int reg = 0; reg < 4; reg++) {
        float ps = 0.f, pd = 0.f;
        #pragma unroll
        for (int c4 = 0; c4 < 4; c4++) {
            ps = fmaf(acc[c4][reg], aS[c4], ps);
            pd = fmaf(acc[c4][reg], aD[c4], pd);
        }
        #pragma unroll
        for (int off = 1; off < 16; off <<= 1) {
            ps += __shfl_xor(ps, off, 64);
            pd += __shfl_xor(pd, off, 64);
        }
        if (n16 == 0) {
            const long row = rowbase + quad*4 + reg;
            es_g[(long)w * BN + row] = ps;
            ed_g[(long)w * BN + row] = pd;
        }
    }
}

// ---------------- Kernel B: dbuf LDS + 2-set register prefetch (2-tile slack) ----------------
__global__ __launch_bounds__(256, 2) void gat_attn(
    const int* __restrict__ adj, const ushort* __restrict__ h_gB,
    const float* __restrict__ es_g, const float* __restrict__ ed_g,
    float* __restrict__ out)
{
    __shared__ ushort hT[2][COLS * HSTR];   // 2 x 20 KB
    __shared__ ushort pT[2][TN * PSTR];     // 2 x 4.25 KB
    __shared__ float  l_lds[TN * Hh];

    const int j    = threadIdx.x;
    const int w    = j >> 6, lane = j & 63, quad = lane >> 4, n16 = lane & 15;
    const int mi   = lane & 31, hh = lane >> 5;
    const int b    = blockIdx.y;
    const int n0   = blockIdx.x * TN;
    const long rowb = (long)b * Nsz + n0;

    f32x2 es2[4];
    #pragma unroll
    for (int r4 = 0; r4 < 4; r4++)
        es2[r4] = (f32x2){ es_g[(long)(hh*2 + 0) * BN + rowb + w*4 + r4],
                           es_g[(long)(hh*2 + 1) * BN + rowb + w*4 + r4] };

    f32x4 acc[4];
    #pragma unroll
    for (int c4 = 0; c4 < 4; c4++)
        #pragma unroll
        for (int r = 0; r < 4; r++) acc[c4][r] = 0.f;

    f32x2 l2p[4];
    #pragma unroll
    for (int r4 = 0; r4 < 4; r4++) l2p[r4] = (f32x2){0.f, 0.f};

    short8 hr[2][4]; int ar[2][4]; f32x2 edr[2];
    const short8* hb8 = (const short8*)h_gB;

#define PREFETCH(t, S) {                                                        \
    const short8* g = hb8 + (long)(b*32 + (t)) * 1024;                          \
    hr[S][0] = g[j];     hr[S][1] = g[j+256];                                   \
    hr[S][2] = g[j+512]; hr[S][3] = g[j+768];                                   \
    const int m0p = (t) * TM;                                                   \
    _Pragma("unroll")                                                           \
    for (int r4 = 0; r4 < 4; r4++)                                              \
        ar[S][r4] = adj[(rowb + w*4 + r4) * (long)Nsz + m0p + mi];              \
    edr[S] = (f32x2){ ed_g[(long)(hh*2 + 0) * BN + (long)b * Nsz + m0p + mi],   \
                      ed_g[(long)(hh*2 + 1) * BN + (long)b * Nsz + m0p + mi] }; }

#define STAGE(buf, S) {                                                         \
    _Pragma("unroll")                                                           \
    for (int i = 0; i < 4; i++) {                                               \
        const int s = j + 256*i;                                                \
        *(short8*)(&hT[buf][(s >> 2) * HSTR + (s & 3) * 8]) = hr[S][i]; } }

#define PHASE_S(buf, S) {                                                       \
    _Pragma("unroll")                                                           \
    for (int r4 = 0; r4 < 4; r4++) {                                            \
        f32x2 s2 = es2[r4] + edr[S];                                            \
        s2 = __builtin_elementwise_max(s2, s2 * 0.2f);                          \
        s2 = s2 - SHIFT;                                                        \
        float e0 = __expf(s2.x), e1 = __expf(s2.y);                             \
        const bool keep = ar[S][r4] > 0;                                        \
        uint pk = cvt_pk2(keep ? e0 : 0.f, keep ? e1 : 0.f);                    \
        pT[buf][(w*4 + r4) * PSTR + (hh*2 + 0) * TM + mi] = (ushort)(pk & 0xFFFFu); \
        pT[buf][(w*4 + r4) * PSTR + (hh*2 + 1) * TM + mi] = (ushort)(pk >> 16); \
        l2p[r4] += (f32x2){ __uint_as_float(pk << 16),                          \
                            __uint_as_float(pk & 0xFFFF0000u) }; } }

#define PHASE_A(buf) {                                                          \
    short8 afp = *(const short8*)(&pT[buf][n16 * PSTR + w * TM + quad * 8]);    \
    _Pragma("unroll")                                                           \
    for (int c4 = 0; c4 < 4; c4++) {                                            \
        short8 bfv = *(const short8*)(&hT[buf][(w*64 + c4*16 + n16) * HSTR + quad * 8]); \
        acc[c4] = __builtin_amdgcn_mfma_f32_16x16x32_bf16(afp, bfv, acc[c4], 0, 0, 0); } }

    // prologue: tile0 staged from set0; sets hold tiles t+1 (set (t+1)&1) and t+2
    PREFETCH(0, 0); PREFETCH(1, 1);
    STAGE(0, 0); PHASE_S(0, 0);
    PREFETCH(2, 0);
    __syncthreads();

    for (int tt = 0; tt < 16; tt++) {
        const int t0 = 2 * tt;
        // body t0 (even): stage tile t0+1 from set1, refill set1 with t0+3
        if (t0 < 31) {
            STAGE(1, 1); PHASE_S(1, 1);
            if (t0 + 3 < 32) PREFETCH(t0 + 3, 1);
        }
        PHASE_A(0);
        __syncthreads();
        // body t0+1 (odd): stage tile t0+2 from set0, refill set0 with t0+4
        if (t0 + 1 < 31) {
            STAGE(0, 0); PHASE_S(0, 0);
            if (t0 + 4 < 32) PREFETCH(t0 + 4, 0);
        }
        PHASE_A(1);
        __syncthreads();
    }

    // ---- epilogue ----
    #pragma unroll
    for (int r4 = 0; r4 < 4; r4++)
        #pragma unroll
        for (int ii = 0; ii < 2; ii++) {
            float lp = ii ? l2p[r4].y : l2p[r4].x;
            #pragma unroll
            for (int off = 1; off < 32; off <<= 1) lp += __shfl_xor(lp, off, 64);
            if (mi == 0) l_lds[(w*4 + r4) * Hh + hh*2 + ii] = lp;
        }
    __syncthreads();

    float* o_lds = (float*)&hT[0][0];   // 16 KB, disjoint from hT[1]/pT[1]
    float rinv[4];
    #pragma unroll
    for (int reg = 0; reg < 4; reg++)
        rinv[reg] = 0.25f / l_lds[(quad*4 + reg) * Hh + w];
    #pragma unroll
    for (int c4 = 0; c4 < 4; c4++)
        #pragma unroll
        for (int reg = 0; reg < 4; reg++)
            o_lds[(w * TN + quad*4 + reg) * FO + c4*16 + n16] = acc[c4][reg] * rinv[reg];
    __syncthreads();

    {
        const int f2 = j & 63, rb = j >> 6;
        #pragma unroll
        for (int i = 0; i < 4; i++) {
            const int r = i*4 + rb;
            const float sum = o_lds[(0*TN + r)*FO + f2] + o_lds[(1*TN + r)*FO + f2]
                            + o_lds[(2*TN + r)*FO + f2] + o_lds[(3*TN + r)*FO + f2];
            out[(rowb + r) * FO + f2] = sum;
        }
    }
#undef PREFETCH
#undef STAGE
#undef PHASE_S
#undef PHASE_A
}

extern "C" void kernel_launch(void* const* d_in, const int* in_sizes, int n_in,
                              void* d_out, int out_size, void* d_ws, size_t ws_size,
                              hipStream_t stream) {
    const float* x   = (const float*)d_in[0];   // (8,1024,128) f32
    const int*   adj = (const int*)d_in[1];     // (8,1024,1024) i32
    const float* W   = (const float*)d_in[2];   // (128,256) f32
    const float* a   = (const float*)d_in[3];   // (4,128) f32
    float* out = (float*)d_out;                 // (8,1024,64) f32

    // ws: Wt bf16 (64KB) | h_gB bf16 (4MB) | es (128KB) | ed (128KB)
    ushort* Wt   = (ushort*)d_ws;
    ushort* h_gB = Wt + (size_t)COLS * FIN;
    float*  es_g = (float*)(h_gB + (size_t)BN * COLS);
    float*  ed_g = es_g + (size_t)Hh * BN;

    gat_prep<<<dim3(8),            dim3(256), 0, stream>>>(W, Wt);
    gat_proj<<<dim3(Bsz*Nsz/16),   dim3(256), 0, stream>>>(x, Wt, a, h_gB, es_g, ed_g);
    gat_attn<<<dim3(Nsz/TN, Bsz),  dim3(256), 0, stream>>>(adj, h_gB, es_g, ed_g, out);
}